// Round 2
// baseline (209.199 us; speedup 1.0000x reference)
//
#include <hip/hip_runtime.h>

#define S_LEN 2048
#define D 256
#define BATCH 64
#define CHUNK 64

// ---------------------------------------------------------------------------
// Kernel 1: row-wise argmax (first-max semantics, like jnp.argmax).
// grid = 2*B = 128 blocks, 256 threads. Row r of score_soft flat [2*B, S].
// ---------------------------------------------------------------------------
__global__ void argmax_kernel(const float* __restrict__ score,
                              int* __restrict__ out_idx) {
    const int row = blockIdx.x;                 // r = k*64 + b, k in {0,1}
    const float* p = score + (size_t)row * S_LEN;
    const int t = threadIdx.x;

    float best = -INFINITY;
    int bidx = 0x7fffffff;
    for (int i = t; i < S_LEN; i += 256) {      // ascending i per thread
        float v = p[i];
        if (v > best) { best = v; bidx = i; }   // ascending i => first-max kept
    }

    __shared__ float sval[256];
    __shared__ int   sidx[256];
    sval[t] = best; sidx[t] = bidx;
    __syncthreads();
    for (int off = 128; off > 0; off >>= 1) {
        if (t < off) {
            float v2 = sval[t + off]; int i2 = sidx[t + off];
            if (v2 > sval[t] || (v2 == sval[t] && i2 < sidx[t])) {
                sval[t] = v2; sidx[t] = i2;
            }
        }
        __syncthreads();
    }
    if (t == 0) out_idx[row] = sidx[0];
}

// ---------------------------------------------------------------------------
// Kernel 2: ragged span sums of doc_encoding rows.
// grid = (S/CHUNK, 128).  blockIdx.y = r in [0,128): r<64 hard span (from ws
// argmax), r>=64 gold span (from answer_idx input).  b = r & 63.
// Each block handles CHUNK rows' intersection with [lo, hi]; 4 waves each
// take every 4th row; one float4/lane covers a full 256-f32 row per wave.
// ---------------------------------------------------------------------------
__global__ void spansum_kernel(const float* __restrict__ doc,
                               const int* __restrict__ hard_idx,
                               const int* __restrict__ answer_idx,
                               float* __restrict__ acc) {
    const int r = blockIdx.y;
    const int b = r & 63;
    int lo, hi;
    if (r < 64) { lo = hard_idx[b];   hi = hard_idx[64 + b]; }
    else        { lo = answer_idx[b]; hi = answer_idx[64 + b]; }

    const int c0 = blockIdx.x * CHUNK;
    const int s0 = max(lo, c0);
    const int s1 = min(hi + 1, c0 + CHUNK);
    if (s0 >= s1) return;                       // chunk outside span (uniform)

    const int t    = threadIdx.x;
    const int wave = t >> 6;                    // 0..3
    const int lane = t & 63;                    // float4 column group

    const float* base = doc + (size_t)b * S_LEN * D + lane * 4;
    float4 sum = make_float4(0.f, 0.f, 0.f, 0.f);
    int s = s0 + wave;
    for (; s + 4 < s1; s += 8) {                // 2 loads in flight
        float4 v0 = *reinterpret_cast<const float4*>(base + (size_t)s * D);
        float4 v1 = *reinterpret_cast<const float4*>(base + (size_t)(s + 4) * D);
        sum.x += v0.x + v1.x; sum.y += v0.y + v1.y;
        sum.z += v0.z + v1.z; sum.w += v0.w + v1.w;
    }
    if (s < s1) {
        float4 v0 = *reinterpret_cast<const float4*>(base + (size_t)s * D);
        sum.x += v0.x; sum.y += v0.y; sum.z += v0.z; sum.w += v0.w;
    }

    __shared__ float lds[4][D];
    *reinterpret_cast<float4*>(&lds[wave][lane * 4]) = sum;
    __syncthreads();

    // column t reduced across the 4 waves, one atomic per (r, t) per chunk
    float tot = lds[0][t] + lds[1][t] + lds[2][t] + lds[3][t];
    atomicAdd(&acc[(size_t)r * D + t], tot);
}

// ---------------------------------------------------------------------------
// Kernel 3: tiny GEMM [128,256] x [256,256] + |span| * bias -> d_out.
// grid = 128 blocks (one output row), 256 threads (one output column).
// W reads coalesced per k; W (256 KB) is L2-resident across blocks.
// ---------------------------------------------------------------------------
__global__ void mlp_kernel(const float* __restrict__ acc,
                           const int* __restrict__ hard_idx,
                           const int* __restrict__ answer_idx,
                           const float* __restrict__ W,
                           const float* __restrict__ bvec,
                           float* __restrict__ out) {
    const int r = blockIdx.x;
    const int b = r & 63;
    int lo, hi;
    if (r < 64) { lo = hard_idx[b];   hi = hard_idx[64 + b]; }
    else        { lo = answer_idx[b]; hi = answer_idx[64 + b]; }
    const float cnt = (hi >= lo) ? (float)(hi - lo + 1) : 0.0f;

    const int t = threadIdx.x;
    __shared__ float av[D];
    av[t] = acc[(size_t)r * D + t];
    __syncthreads();

    float sum = cnt * bvec[t];
#pragma unroll 8
    for (int k = 0; k < D; ++k) {
        sum += av[k] * W[(size_t)k * D + t];
    }
    out[(size_t)r * D + t] = sum;               // [0,64): hard, [64,128): gold
}

// ---------------------------------------------------------------------------
extern "C" void kernel_launch(void* const* d_in, const int* in_sizes, int n_in,
                              void* d_out, int out_size, void* d_ws, size_t ws_size,
                              hipStream_t stream) {
    const float* doc        = (const float*)d_in[0];  // [64,2048,256] f32
    const float* score      = (const float*)d_in[1];  // [2,64,2048]   f32
    const int*   answer_idx = (const int*)  d_in[2];  // [2,64]        i32
    const float* W          = (const float*)d_in[3];  // [256,256]     f32
    const float* bvec       = (const float*)d_in[4];  // [256]         f32
    float*       out        = (float*)d_out;          // [2,64,256]    f32

    int*   hard_idx = (int*)d_ws;                     // 128 ints
    float* acc      = (float*)((char*)d_ws + 1024);   // [128,256] f32 = 128 KB

    hipMemsetAsync(acc, 0, (size_t)2 * BATCH * D * sizeof(float), stream);

    argmax_kernel<<<dim3(2 * BATCH), dim3(256), 0, stream>>>(score, hard_idx);

    dim3 g2(S_LEN / CHUNK, 2 * BATCH);
    spansum_kernel<<<g2, dim3(256), 0, stream>>>(doc, hard_idx, answer_idx, acc);

    mlp_kernel<<<dim3(2 * BATCH), dim3(256), 0, stream>>>(acc, hard_idx, answer_idx,
                                                          W, bvec, out);
}

// Round 5
// 204.964 us; speedup vs baseline: 1.0207x; 1.0207x over previous
//
#include <hip/hip_runtime.h>

#define S_LEN 2048
#define D 256
#define BATCH 64
#define CHUNK 64

// ---------------------------------------------------------------------------
// Kernel 1: row argmax (first-max, jnp semantics) + zero the accumulator.
// grid = 128 blocks, 256 threads. Block `row` handles score row `row`
// (rows 0..63 = start scores, 64..127 = end scores) AND zeroes acc row `row`
// (replaces the separate hipMemsetAsync dispatch; safe because spansum only
// runs after this kernel completes in stream order).
// Each thread reads exactly 8 contiguous floats (2x float4) -> no loop.
// ---------------------------------------------------------------------------
__global__ void argmax_zero_kernel(const float* __restrict__ score,
                                   int* __restrict__ hard_idx,
                                   float* __restrict__ acc) {
    const int row = blockIdx.x;
    const int t   = threadIdx.x;

    acc[(size_t)row * D + t] = 0.0f;

    const float4* p = reinterpret_cast<const float4*>(score + (size_t)row * S_LEN);
    const float4 a = p[2 * t];
    const float4 b = p[2 * t + 1];
    const float v[8] = {a.x, a.y, a.z, a.w, b.x, b.y, b.z, b.w};

    float best = v[0];
    int   bidx = 8 * t;
#pragma unroll
    for (int j = 1; j < 8; ++j)
        if (v[j] > best) { best = v[j]; bidx = 8 * t + j; }  // ascending j => first-max

    __shared__ float sval[256];
    __shared__ int   sidx[256];
    sval[t] = best; sidx[t] = bidx;
    __syncthreads();
    for (int off = 128; off > 0; off >>= 1) {
        if (t < off) {
            float v2 = sval[t + off]; int i2 = sidx[t + off];
            if (v2 > sval[t] || (v2 == sval[t] && i2 < sidx[t])) {
                sval[t] = v2; sidx[t] = i2;
            }
        }
        __syncthreads();
    }
    if (t == 0) hard_idx[row] = sidx[0];
}

// ---------------------------------------------------------------------------
// Kernel 2: ragged span sums of doc_encoding rows.
// grid = (S/CHUNK, 128). blockIdx.y = r: r<64 hard span (ws argmax),
// r>=64 gold span (answer_idx input). b = r & 63.
// Each block covers CHUNK rows' intersection with [lo,hi]; 4 waves stride
// rows; one float4/lane => a wave-load covers one full 256-f32 row.
// ---------------------------------------------------------------------------
__global__ void spansum_kernel(const float* __restrict__ doc,
                               const int* __restrict__ hard_idx,
                               const int* __restrict__ answer_idx,
                               float* __restrict__ acc) {
    const int r = blockIdx.y;
    const int b = r & 63;
    int lo, hi;
    if (r < 64) { lo = hard_idx[b];   hi = hard_idx[64 + b]; }
    else        { lo = answer_idx[b]; hi = answer_idx[64 + b]; }

    const int c0 = blockIdx.x * CHUNK;
    const int s0 = max(lo, c0);
    const int s1 = min(hi + 1, c0 + CHUNK);
    if (s0 >= s1) return;                       // chunk outside span (uniform exit)

    const int t    = threadIdx.x;
    const int wave = t >> 6;                    // 0..3
    const int lane = t & 63;                    // float4 column group

    const float* base = doc + (size_t)b * S_LEN * D + lane * 4;
    float4 sum = make_float4(0.f, 0.f, 0.f, 0.f);
    int s = s0 + wave;
    for (; s + 4 < s1; s += 8) {                // 2 loads in flight
        float4 v0 = *reinterpret_cast<const float4*>(base + (size_t)s * D);
        float4 v1 = *reinterpret_cast<const float4*>(base + (size_t)(s + 4) * D);
        sum.x += v0.x + v1.x; sum.y += v0.y + v1.y;
        sum.z += v0.z + v1.z; sum.w += v0.w + v1.w;
    }
    if (s < s1) {
        float4 v0 = *reinterpret_cast<const float4*>(base + (size_t)s * D);
        sum.x += v0.x; sum.y += v0.y; sum.z += v0.z; sum.w += v0.w;
    }

    __shared__ float lds[4][D];
    *reinterpret_cast<float4*>(&lds[wave][lane * 4]) = sum;
    __syncthreads();

    float tot = lds[0][t] + lds[1][t] + lds[2][t] + lds[3][t];
    atomicAdd(&acc[(size_t)r * D + t], tot);
}

// ---------------------------------------------------------------------------
// Kernel 3: tiny GEMM [128,256] x [256,256] + |span| * bias -> d_out.
// grid = 128 blocks (one output row), 256 threads (one output column).
// W reads coalesced per k; W (256 KB) is L2-resident across blocks.
// ---------------------------------------------------------------------------
__global__ void mlp_kernel(const float* __restrict__ acc,
                           const int* __restrict__ hard_idx,
                           const int* __restrict__ answer_idx,
                           const float* __restrict__ W,
                           const float* __restrict__ bvec,
                           float* __restrict__ out) {
    const int r = blockIdx.x;
    const int b = r & 63;
    int lo, hi;
    if (r < 64) { lo = hard_idx[b];   hi = hard_idx[64 + b]; }
    else        { lo = answer_idx[b]; hi = answer_idx[64 + b]; }
    const float cnt = (hi >= lo) ? (float)(hi - lo + 1) : 0.0f;

    const int t = threadIdx.x;
    __shared__ float av[D];
    av[t] = acc[(size_t)r * D + t];
    __syncthreads();

    float sum = cnt * bvec[t];
#pragma unroll 8
    for (int k = 0; k < D; ++k) {
        sum += av[k] * W[(size_t)k * D + t];
    }
    out[(size_t)r * D + t] = sum;               // [0,64): hard, [64,128): gold
}

// ---------------------------------------------------------------------------
extern "C" void kernel_launch(void* const* d_in, const int* in_sizes, int n_in,
                              void* d_out, int out_size, void* d_ws, size_t ws_size,
                              hipStream_t stream) {
    const float* doc        = (const float*)d_in[0];  // [64,2048,256] f32
    const float* score      = (const float*)d_in[1];  // [2,64,2048]   f32
    const int*   answer_idx = (const int*)  d_in[2];  // [2,64]        i32
    const float* W          = (const float*)d_in[3];  // [256,256]     f32
    const float* bvec       = (const float*)d_in[4];  // [256]         f32
    float*       out        = (float*)d_out;          // [2,64,256]    f32

    int*   hard_idx = (int*)d_ws;                     // 128 ints
    float* acc      = (float*)((char*)d_ws + 1024);   // [128,256] f32 = 128 KB

    argmax_zero_kernel<<<dim3(2 * BATCH), dim3(256), 0, stream>>>(score, hard_idx, acc);

    dim3 g2(S_LEN / CHUNK, 2 * BATCH);
    spansum_kernel<<<g2, dim3(256), 0, stream>>>(doc, hard_idx, answer_idx, acc);

    mlp_kernel<<<dim3(2 * BATCH), dim3(256), 0, stream>>>(acc, hard_idx, answer_idx,
                                                          W, bvec, out);
}

// Round 7
// 203.463 us; speedup vs baseline: 1.0282x; 1.0074x over previous
//
#include <hip/hip_runtime.h>

#define S_LEN 2048
#define D 256
#define BATCH 64
#define CHUNK 64
#define NCHUNK (S_LEN / CHUNK)   // 32

// ---------------------------------------------------------------------------
// Kernel 1: fused span-sum.  grid = (NCHUNK, 128), 256 threads.
// r = blockIdx.y: r<64 -> hard span, recomputed IN-BLOCK by cooperative
// argmax over score rows b and 64+b (deterministic, so all 32 chunk-blocks
// of a row agree); r>=64 -> gold span from answer_idx.
// Each block writes its partial sum to a UNIQUE slot acc_part[r][chunk][:]
// (zeros when inactive) and its row count to cnt_part[r][chunk] -> no
// atomics, no pre-zeroed buffer, no ordering dependency on any prior kernel.
// ---------------------------------------------------------------------------
__global__ void spansum_fused_kernel(const float* __restrict__ doc,
                                     const float* __restrict__ score,
                                     const int* __restrict__ answer_idx,
                                     float* __restrict__ acc_part,
                                     int* __restrict__ cnt_part) {
    const int chunk = blockIdx.x;
    const int r     = blockIdx.y;
    const int b     = r & 63;
    const int t     = threadIdx.x;

    __shared__ float sv0[256]; __shared__ int si0[256];
    __shared__ float sv1[256]; __shared__ int si1[256];
    __shared__ float lds[4][D];

    int lo, hi;
    if (r < 64) {
        // cooperative first-max argmax of score rows b (start) and 64+b (end)
        const float4* p0 = reinterpret_cast<const float4*>(score + (size_t)b * S_LEN);
        const float4* p1 = reinterpret_cast<const float4*>(score + (size_t)(64 + b) * S_LEN);
        const float4 a0 = p0[2 * t], b0 = p0[2 * t + 1];
        const float4 a1 = p1[2 * t], b1 = p1[2 * t + 1];
        const float v0[8] = {a0.x, a0.y, a0.z, a0.w, b0.x, b0.y, b0.z, b0.w};
        const float v1[8] = {a1.x, a1.y, a1.z, a1.w, b1.x, b1.y, b1.z, b1.w};
        float best0 = v0[0]; int idx0 = 8 * t;
        float best1 = v1[0]; int idx1 = 8 * t;
#pragma unroll
        for (int j = 1; j < 8; ++j) {
            if (v0[j] > best0) { best0 = v0[j]; idx0 = 8 * t + j; }  // ascending j => first-max
            if (v1[j] > best1) { best1 = v1[j]; idx1 = 8 * t + j; }
        }
        sv0[t] = best0; si0[t] = idx0;
        sv1[t] = best1; si1[t] = idx1;
        __syncthreads();
        for (int off = 128; off > 0; off >>= 1) {
            if (t < off) {
                float v; int i;
                v = sv0[t + off]; i = si0[t + off];
                if (v > sv0[t] || (v == sv0[t] && i < si0[t])) { sv0[t] = v; si0[t] = i; }
                v = sv1[t + off]; i = si1[t + off];
                if (v > sv1[t] || (v == sv1[t] && i < si1[t])) { sv1[t] = v; si1[t] = i; }
            }
            __syncthreads();
        }
        lo = si0[0]; hi = si1[0];
    } else {
        lo = answer_idx[b]; hi = answer_idx[64 + b];
    }

    const int c0 = chunk * CHUNK;
    const int s0 = max(lo, c0);
    const int s1 = min(hi + 1, c0 + CHUNK);

    const int wave = t >> 6;                    // 0..3
    const int lane = t & 63;                    // float4 column group

    float4 sum = make_float4(0.f, 0.f, 0.f, 0.f);
    if (s0 < s1) {
        const float* base = doc + (size_t)b * S_LEN * D + lane * 4;
        int s = s0 + wave;
        for (; s + 4 < s1; s += 8) {            // 2 loads in flight
            float4 u0 = *reinterpret_cast<const float4*>(base + (size_t)s * D);
            float4 u1 = *reinterpret_cast<const float4*>(base + (size_t)(s + 4) * D);
            sum.x += u0.x + u1.x; sum.y += u0.y + u1.y;
            sum.z += u0.z + u1.z; sum.w += u0.w + u1.w;
        }
        if (s < s1) {
            float4 u0 = *reinterpret_cast<const float4*>(base + (size_t)s * D);
            sum.x += u0.x; sum.y += u0.y; sum.z += u0.z; sum.w += u0.w;
        }
    }

    *reinterpret_cast<float4*>(&lds[wave][lane * 4]) = sum;
    __syncthreads();

    const float tot = lds[0][t] + lds[1][t] + lds[2][t] + lds[3][t];
    acc_part[((size_t)r * NCHUNK + chunk) * D + t] = tot;      // unique slot, no atomics
    if (t == 0) cnt_part[r * NCHUNK + chunk] = (s1 > s0) ? (s1 - s0) : 0;
}

// ---------------------------------------------------------------------------
// Kernel 2: reduce 32 partials + tiny GEMM [128,256] x [256,256] + cnt*bias.
// grid = 128 blocks (one output row), 256 threads (one output column).
// W reads coalesced per k; W (256 KB) is L2-resident across blocks.
// ---------------------------------------------------------------------------
__global__ void mlp_kernel(const float* __restrict__ acc_part,
                           const int* __restrict__ cnt_part,
                           const float* __restrict__ W,
                           const float* __restrict__ bvec,
                           float* __restrict__ out) {
    const int r = blockIdx.x;
    const int t = threadIdx.x;

    __shared__ float av[D];
    float s = 0.0f;
#pragma unroll 4
    for (int c = 0; c < NCHUNK; ++c)
        s += acc_part[((size_t)r * NCHUNK + c) * D + t];
    av[t] = s;

    int cnt = 0;
#pragma unroll 4
    for (int c = 0; c < NCHUNK; ++c)            // uniform broadcast loads
        cnt += cnt_part[r * NCHUNK + c];
    __syncthreads();

    float sum = (float)cnt * bvec[t];
#pragma unroll 8
    for (int k = 0; k < D; ++k) {
        sum += av[k] * W[(size_t)k * D + t];
    }
    out[(size_t)r * D + t] = sum;               // [0,64): hard, [64,128): gold
}

// ---------------------------------------------------------------------------
extern "C" void kernel_launch(void* const* d_in, const int* in_sizes, int n_in,
                              void* d_out, int out_size, void* d_ws, size_t ws_size,
                              hipStream_t stream) {
    const float* doc        = (const float*)d_in[0];  // [64,2048,256] f32
    const float* score      = (const float*)d_in[1];  // [2,64,2048]   f32
    const int*   answer_idx = (const int*)  d_in[2];  // [2,64]        i32
    const float* W          = (const float*)d_in[3];  // [256,256]     f32
    const float* bvec       = (const float*)d_in[4];  // [256]         f32
    float*       out        = (float*)d_out;          // [2,64,256]    f32

    float* acc_part = (float*)d_ws;                               // [128][32][256] f32 = 4 MB
    int*   cnt_part = (int*)((char*)d_ws + (size_t)128 * NCHUNK * D * sizeof(float));

    dim3 g1(NCHUNK, 2 * BATCH);
    spansum_fused_kernel<<<g1, dim3(256), 0, stream>>>(doc, score, answer_idx,
                                                       acc_part, cnt_part);

    mlp_kernel<<<dim3(2 * BATCH), dim3(256), 0, stream>>>(acc_part, cnt_part,
                                                          W, bvec, out);
}